// Round 1
// baseline (268.575 us; speedup 1.0000x reference)
//
#include <hip/hip_runtime.h>

#define N_NODES_C 131072
#define N_EDGES_C 8388608
#define N_GRAPHS_C 64
#define NBLK 1024
#define BLK 256

__device__ __forceinline__ int lower_bound_dev(const int* a, int n, int v) {
    int lo = 0, hi = n;
    while (lo < hi) { int mid = (lo + hi) >> 1; if (a[mid] < v) lo = mid + 1; else hi = mid; }
    return lo;
}

// Pack {pos.x, pos.y, size.x, size.y} per node -> one 16B gather instead of two 8B.
__global__ void build_A_kernel(const float2* __restrict__ pos, const float2* __restrict__ sz,
                               float4* __restrict__ A) {
    int n = blockIdx.x * blockDim.x + threadIdx.x;
    if (n < N_NODES_C) {
        float2 p = pos[n]; float2 s = sz[n];
        A[n] = make_float4(p.x, p.y, s.x, s.y);
    }
}

// Edge pass 1: per-graph {sum r, sum r^2, sum normalized_overlap, edge count}.
__global__ __launch_bounds__(BLK) void pass1_kernel(
    const int* __restrict__ idx0, const int* __restrict__ idx1,
    const float* __restrict__ attr, const float4* __restrict__ A,
    const int* __restrict__ batch,
    float* __restrict__ rsum_p, float* __restrict__ r2_p,
    float* __restrict__ ov_p, float* __restrict__ cnt_p) {
    __shared__ float sb_r[N_GRAPHS_C], sb_r2[N_GRAPHS_C], sb_ov[N_GRAPHS_C], sb_c[N_GRAPHS_C];
    int tid = threadIdx.x;
    if (tid < N_GRAPHS_C) { sb_r[tid] = 0.f; sb_r2[tid] = 0.f; sb_ov[tid] = 0.f; sb_c[tid] = 0.f; }
    __syncthreads();
    const int4* v0 = (const int4*)idx0;
    const int4* v1 = (const int4*)idx1;
    const float4* va = (const float4*)attr;
    const int nvec = N_EDGES_C / 4;
    for (int i = blockIdx.x * BLK + tid; i < nvec; i += NBLK * BLK) {
        int4 s4 = v0[i]; int4 t4 = v1[i]; float4 d4 = va[i];
        int   ss[4] = {s4.x, s4.y, s4.z, s4.w};
        int   tt[4] = {t4.x, t4.y, t4.z, t4.w};
        float dd[4] = {d4.x, d4.y, d4.z, d4.w};
        #pragma unroll
        for (int k = 0; k < 4; ++k) {
            int s = ss[k], t = tt[k];
            float d = dd[k];
            float4 as_ = A[s];
            float4 at_ = A[t];
            int g = batch[s];
            float dx = as_.x - at_.x, dy = as_.y - at_.y;
            float eu = sqrtf(dx * dx + dy * dy);
            float r = eu / d;
            atomicAdd(&sb_r[g], r);
            atomicAdd(&sb_r2[g], r * r);
            float ox = fmaxf((as_.z + at_.z) * 0.5f - fabsf(dx), 0.f);
            float oy = fmaxf((as_.w + at_.w) * 0.5f - fabsf(dy), 0.f);
            float tot = as_.z + as_.w + at_.z + at_.w;
            float nov = (ox * oy) / tot;
            atomicAdd(&sb_ov[g], nov);
            atomicAdd(&sb_c[g], 1.f);
        }
    }
    __syncthreads();
    if (tid < N_GRAPHS_C) {
        int o = tid * NBLK + blockIdx.x;
        rsum_p[o] = sb_r[tid];
        r2_p[o]   = sb_r2[tid];
        ov_p[o]   = sb_ov[tid];
        cnt_p[o]  = sb_c[tid];
    }
}

// Per-graph: scale = sum(r^2)/sum(r); graph_overlap = sum(nov)/max(cnt,1); node count via
// binary search on sorted batch_idx.
__global__ void reduce1_kernel(const float* __restrict__ rsum_p, const float* __restrict__ r2_p,
                               const float* __restrict__ ov_p, const float* __restrict__ cnt_p,
                               const int* __restrict__ batch,
                               float* __restrict__ scale, float* __restrict__ gov,
                               float* __restrict__ gsize) {
    int g = blockIdx.x, tid = threadIdx.x;
    float a = 0.f, b = 0.f, c = 0.f, d = 0.f;
    for (int i = tid; i < NBLK; i += 256) {
        a += rsum_p[g * NBLK + i];
        b += r2_p[g * NBLK + i];
        c += ov_p[g * NBLK + i];
        d += cnt_p[g * NBLK + i];
    }
    __shared__ float sa[256], sb[256], sc[256], sd[256];
    sa[tid] = a; sb[tid] = b; sc[tid] = c; sd[tid] = d;
    __syncthreads();
    for (int s = 128; s > 0; s >>= 1) {
        if (tid < s) { sa[tid] += sa[tid+s]; sb[tid] += sb[tid+s]; sc[tid] += sc[tid+s]; sd[tid] += sd[tid+s]; }
        __syncthreads();
    }
    if (tid == 0) {
        scale[g] = sb[0] / sa[0];
        gov[g]   = sc[0] / fmaxf(sd[0], 1.f);
        int lo = lower_bound_dev(batch, N_NODES_C, g);
        int hi = lower_bound_dev(batch, N_NODES_C, g + 1);
        gsize[g] = (float)(hi - lo);
    }
}

// Pack {pos/scale, graph_id_bits} per node for pass 2 (single 16B gather, no batch re-gather).
__global__ void build_B_kernel(const float2* __restrict__ pos, const int* __restrict__ batch,
                               const float* __restrict__ scale, float4* __restrict__ B) {
    int n = blockIdx.x * blockDim.x + threadIdx.x;
    if (n < N_NODES_C) {
        int g = batch[n];
        float s = scale[g];
        float2 p = pos[n];
        B[n] = make_float4(p.x / s, p.y / s, __int_as_float(g), 0.f);
    }
}

// Edge pass 2: per-graph stress sum with scaled positions.
__global__ __launch_bounds__(BLK) void pass2_kernel(
    const int* __restrict__ idx0, const int* __restrict__ idx1,
    const float* __restrict__ attr, const float4* __restrict__ B,
    float* __restrict__ st_p) {
    __shared__ float sbn[N_GRAPHS_C];
    int tid = threadIdx.x;
    if (tid < N_GRAPHS_C) sbn[tid] = 0.f;
    __syncthreads();
    const int4* v0 = (const int4*)idx0;
    const int4* v1 = (const int4*)idx1;
    const float4* va = (const float4*)attr;
    const int nvec = N_EDGES_C / 4;
    for (int i = blockIdx.x * BLK + tid; i < nvec; i += NBLK * BLK) {
        int4 s4 = v0[i]; int4 t4 = v1[i]; float4 d4 = va[i];
        int   ss[4] = {s4.x, s4.y, s4.z, s4.w};
        int   tt[4] = {t4.x, t4.y, t4.z, t4.w};
        float dd[4] = {d4.x, d4.y, d4.z, d4.w};
        #pragma unroll
        for (int k = 0; k < 4; ++k) {
            float4 bs = B[ss[k]];
            float4 bt = B[tt[k]];
            int g = __float_as_int(bs.z);
            float dx = bs.x - bt.x, dy = bs.y - bt.y;
            float eu2 = sqrtf(dx * dx + dy * dy);
            float q = (eu2 - dd[k]) / dd[k];
            atomicAdd(&sbn[g], q * q);
        }
    }
    __syncthreads();
    if (tid < N_GRAPHS_C) st_p[tid * NBLK + blockIdx.x] = sbn[tid];
}

__global__ void reduce2_kernel(const float* __restrict__ st_p, const float* __restrict__ gsize,
                               const float* __restrict__ gov, float* __restrict__ comb) {
    int g = blockIdx.x, tid = threadIdx.x;
    float a = 0.f;
    for (int i = tid; i < NBLK; i += 256) a += st_p[g * NBLK + i];
    __shared__ float sm[256];
    sm[tid] = a;
    __syncthreads();
    for (int s = 128; s > 0; s >>= 1) {
        if (tid < s) sm[tid] += sm[tid + s];
        __syncthreads();
    }
    if (tid == 0) {
        float n = gsize[g];
        comb[g] = sm[0] / (n * n) + gov[g];
    }
}

__global__ void final_kernel(const float* __restrict__ comb, float* __restrict__ out) {
    float v = comb[threadIdx.x];
    #pragma unroll
    for (int off = 32; off > 0; off >>= 1) v += __shfl_down(v, off);
    if (threadIdx.x == 0) out[0] = v * (1.0f / 64.0f);
}

extern "C" void kernel_launch(void* const* d_in, const int* in_sizes, int n_in,
                              void* d_out, int out_size, void* d_ws, size_t ws_size,
                              hipStream_t stream) {
    const float* node_pos   = (const float*)d_in[0];   // (131072, 2)
    const float* node_sizes = (const float*)d_in[1];   // (131072, 2)
    const float* attr       = (const float*)d_in[2];   // (8388608, 1)
    const int*   eidx       = (const int*)d_in[3];     // (2, 8388608)
    const int*   batch      = (const int*)d_in[4];     // (131072,) sorted
    float* out = (float*)d_out;
    float* ws  = (float*)d_ws;

    const int P = N_GRAPHS_C * NBLK;
    float* rsum_p = ws;
    float* r2_p   = ws + P;
    float* ov_p   = ws + 2 * P;
    float* cnt_p  = ws + 3 * P;
    float* st_p   = ws + 4 * P;
    float* scale  = ws + 5 * P;        // 64
    float* gov    = scale + 64;        // 64
    float* gsize  = gov + 64;          // 64
    float* comb   = gsize + 64;        // 64
    float4* A = (float4*)(ws + 5 * P + 256);
    float4* B = A + N_NODES_C;

    const int* idx0 = eidx;
    const int* idx1 = eidx + N_EDGES_C;

    build_A_kernel<<<N_NODES_C / 256, 256, 0, stream>>>((const float2*)node_pos,
                                                        (const float2*)node_sizes, A);
    pass1_kernel<<<NBLK, BLK, 0, stream>>>(idx0, idx1, attr, A, batch,
                                           rsum_p, r2_p, ov_p, cnt_p);
    reduce1_kernel<<<N_GRAPHS_C, 256, 0, stream>>>(rsum_p, r2_p, ov_p, cnt_p, batch,
                                                   scale, gov, gsize);
    build_B_kernel<<<N_NODES_C / 256, 256, 0, stream>>>((const float2*)node_pos, batch, scale, B);
    pass2_kernel<<<NBLK, BLK, 0, stream>>>(idx0, idx1, attr, B, st_p);
    reduce2_kernel<<<N_GRAPHS_C, 256, 0, stream>>>(st_p, gsize, gov, comb);
    final_kernel<<<1, 64, 0, stream>>>(comb, out);
}